// Round 16
// baseline (93.587 us; speedup 1.0000x reference)
//
#include <hip/hip_runtime.h>

#define D 64
#define EPSV 1e-9f

typedef __attribute__((ext_vector_type(8))) short bf8_t;   // 8 x bf16
typedef __attribute__((ext_vector_type(4))) float f4_t;

__device__ inline float bf2f(short u) {
    union { unsigned int i; float f; } v;
    v.i = ((unsigned int)(unsigned short)u) << 16;
    return v.f;
}
__device__ inline unsigned short f2bf(float f) {  // round-nearest-even
    union { float f; unsigned int i; } v; v.f = f;
    unsigned int r = v.i + 0x7fff + ((v.i >> 16) & 1);
    return (unsigned short)(r >> 16);
}

// --- Fused prep: cvt -> 2 planes | wpack | row_off boundary scatter ---
__global__ void prep_kernel(const float* __restrict__ node_feats,
                            const int*   __restrict__ edge_dst,
                            const float* __restrict__ W0,
                            const float* __restrict__ W1,
                            int* __restrict__ row_off,
                            unsigned short* __restrict__ Wpack,
                            unsigned short* __restrict__ XA,   // [n][32] dims 0-31
                            unsigned short* __restrict__ XB,   // [n][32] dims 32-63
                            int n_nodes, int n_edges, int cvtb)
{
    const int bid = blockIdx.x, tid = threadIdx.x;
    if (bid < cvtb) {
        const int i = bid * 256 + tid;
        if (i < n_nodes * 16) {
            const float4 v = ((const float4*)node_feats)[i];
            const int row = i >> 4, c4 = (i & 15) * 4;
            unsigned short* p = (c4 < 32) ? (XA + row * 32 + c4)
                                          : (XB + row * 32 + (c4 - 32));
            p[0] = f2bf(v.x); p[1] = f2bf(v.y); p[2] = f2bf(v.z); p[3] = f2bf(v.w);
        }
    } else if (bid < cvtb + 32) {
        // Wpack[((t*4+kk)*64+lane)*8+j] = W[k][col], k=kk*32+(lane>>4)*8+j, col=t*16+(lane&15)
        const int idx = (bid - cvtb) * 256 + tid;
        const int j = idx & 7, lane = (idx >> 3) & 63, kk = (idx >> 9) & 3, t = idx >> 11;
        const int k = kk * 32 + (lane >> 4) * 8 + j;
        const int d = t * 16 + (lane & 15);
        const float v = (k < D) ? W0[d * D + k] : W1[d * D + (k - D)];
        Wpack[idx] = f2bf(v);
    } else {
        const int i = (bid - cvtb - 32) * 256 + tid;   // i in [0, n_edges]
        if (i <= n_edges) {
            const int prev = (i == 0) ? -1 : edge_dst[i - 1];
            const int cur  = (i == n_edges) ? n_nodes : edge_dst[i];
            for (int n = prev + 1; n <= cur; ++n) row_off[n] = i;
        }
    }
}

// --- Aggregate: PERSISTENT blocks, plane<->XCD affinity.
// Block b (resident whole dispatch): chunk = b&1 -> XCD parity stable.
// Per-XCD gather hot-set = one 3.2MB plane (< 4MB L2). Meta via nt loads,
// M via nt stores (don't evict the plane).
// Wave = 2 nodes (half-wave each); 8 slots x 4 lanes x 16B; 2 gather instrs
// = 32 random 64B lines in flight (same line-MLP as r12).
__global__ __launch_bounds__(256, 8) void aggregate_kernel(
    const unsigned short* __restrict__ XA,   // [n][32]
    const unsigned short* __restrict__ XB,   // [n][32]
    unsigned short* __restrict__ M,          // [n][64]
    const int*   __restrict__ row_off,
    const int*   __restrict__ edge_src,
    const float* __restrict__ edge_w,
    int n_nodes, int nwaves_c)
{
    const int lane  = threadIdx.x & 63;
    const int wib   = threadIdx.x >> 6;
    const int b     = blockIdx.x;
    const int chunk = b & 1;
    const unsigned short* __restrict__ P = chunk ? XB : XA;

    const int h   = lane >> 5;           // half-wave = node select
    const int sid = (lane >> 2) & 7;     // 8 edge slots
    const int fo  = (lane & 3) * 8;      // 16B piece of the 64B plane row

    const int wave_c = (b >> 1) * 4 + wib;   // wave id within this chunk
    const int ntasks = (n_nodes + 1) / 2;

    for (int task = wave_c; task < ntasks; task += nwaves_c) {
        int node = task * 2 + h;
        if (node >= n_nodes) node = n_nodes - 1;

        const int s = row_off[node];
        const int e = row_off[node + 1];
        const int deg = e - s;
        const int od  = __shfl_xor(deg, 32);
        const int degmax = deg > od ? deg : od;   // wave-uniform

        float acc[8];
        #pragma unroll
        for (int m = 0; m < 8; ++m) acc[m] = 0.f;
        float wsum = 0.f;

        {   // groups 0-1 (16 edges/node): batched nt meta, 2 gathers in flight
            float w[2]; int sc[2];
            #pragma unroll
            for (int g = 0; g < 2; ++g) {
                const int  ej = s + g * 8 + sid;
                const bool v  = ej < e;
                w[g]  = v ? __builtin_nontemporal_load(edge_w + ej) : 0.f;
                sc[g] = v ? __builtin_nontemporal_load(edge_src + ej) : 0;
            }
            bf8_t f[2];
            #pragma unroll
            for (int g = 0; g < 2; ++g) f[g] = *(const bf8_t*)(P + sc[g] * 32 + fo);
            #pragma unroll
            for (int g = 0; g < 2; ++g) {
                #pragma unroll
                for (int m = 0; m < 8; ++m) acc[m] = fmaf(w[g], bf2f(f[g][m]), acc[m]);
                wsum += w[g];
            }
        }
        if (degmax > 16) {   // groups 2-3
            float w[2]; int sc[2];
            #pragma unroll
            for (int g = 0; g < 2; ++g) {
                const int  ej = s + 16 + g * 8 + sid;
                const bool v  = ej < e;
                w[g]  = v ? __builtin_nontemporal_load(edge_w + ej) : 0.f;
                sc[g] = v ? __builtin_nontemporal_load(edge_src + ej) : 0;
            }
            bf8_t f[2];
            #pragma unroll
            for (int g = 0; g < 2; ++g) f[g] = *(const bf8_t*)(P + sc[g] * 32 + fo);
            #pragma unroll
            for (int g = 0; g < 2; ++g) {
                #pragma unroll
                for (int m = 0; m < 8; ++m) acc[m] = fmaf(w[g], bf2f(f[g][m]), acc[m]);
                wsum += w[g];
            }
        }
        for (int base = 32; base < degmax; base += 16) {  // rare tail
            float w[2]; int sc[2];
            #pragma unroll
            for (int g = 0; g < 2; ++g) {
                const int  ej = s + base + g * 8 + sid;
                const bool v  = ej < e;
                w[g]  = v ? __builtin_nontemporal_load(edge_w + ej) : 0.f;
                sc[g] = v ? __builtin_nontemporal_load(edge_src + ej) : 0;
            }
            bf8_t f[2];
            #pragma unroll
            for (int g = 0; g < 2; ++g) f[g] = *(const bf8_t*)(P + sc[g] * 32 + fo);
            #pragma unroll
            for (int g = 0; g < 2; ++g) {
                #pragma unroll
                for (int m = 0; m < 8; ++m) acc[m] = fmaf(w[g], bf2f(f[g][m]), acc[m]);
                wsum += w[g];
            }
        }

        // butterfly over slot bits (lane bits 2,3,4) -- within half-wave
        #pragma unroll
        for (int off = 4; off <= 16; off <<= 1) {
            #pragma unroll
            for (int m = 0; m < 8; ++m) acc[m] += __shfl_xor(acc[m], off);
            wsum += __shfl_xor(wsum, off);
        }

        const float inv = 1.0f / (wsum + EPSV);
        if (sid == 0) {                 // 4 lanes/node x 16B = this chunk's 64B
            bf8_t mv;
            #pragma unroll
            for (int m = 0; m < 8; ++m) mv[m] = (short)f2bf(acc[m] * inv);
            __builtin_nontemporal_store(mv, (bf8_t*)(M + node * 64 + chunk * 32 + fo));
        }
    }
}

// --- MFMA GEMM (r12 structure, plane inputs). Wave = one 16-row tile.
template<int OUT_F32>
__global__ __launch_bounds__(256, 4) void gemm_mfma(
    const unsigned short* __restrict__ XA,     // [n][32]
    const unsigned short* __restrict__ XB,     // [n][32]
    const unsigned short* __restrict__ M,      // [n][64]
    const unsigned short* __restrict__ Wpack,  // fragment-packed, 8192 bf16
    const float* __restrict__ b0,
    const float* __restrict__ b1,
    void* __restrict__ outA,                   // f32 out, or next XA
    void* __restrict__ outB,                   // next XB (bf16 path)
    int ntiles, int n_nodes)
{
    const int lane = threadIdx.x & 63;
    const int wib  = threadIdx.x >> 6;
    const int tile = __builtin_amdgcn_readfirstlane(blockIdx.x * 4 + wib);
    if (tile >= ntiles) return;

    bf8_t bfr[4][4];
    #pragma unroll
    for (int t = 0; t < 4; ++t)
        #pragma unroll
        for (int kk = 0; kk < 4; ++kk)
            bfr[t][kk] = *(const bf8_t*)(Wpack + ((t * 4 + kk) * 64 + lane) * 8);

    float bias[4];
    #pragma unroll
    for (int t = 0; t < 4; ++t) {
        const int col = t * 16 + (lane & 15);
        bias[t] = b0[col] + b1[col];
    }

    const int koff = (lane >> 4) * 8;
    const int rowbase = tile * 16;
    int arow = rowbase + (lane & 15); if (arow >= n_nodes) arow = n_nodes - 1;

    bf8_t af[4];
    af[0] = *(const bf8_t*)(XA + arow * 32 + koff);       // k  0..31
    af[1] = *(const bf8_t*)(XB + arow * 32 + koff);       // k 32..63
    af[2] = *(const bf8_t*)(M + arow * 64 + koff);        // k 64..95
    af[3] = *(const bf8_t*)(M + arow * 64 + 32 + koff);   // k 96..127

    f4_t acc[4];
    #pragma unroll
    for (int t = 0; t < 4; ++t) acc[t] = (f4_t){0.f, 0.f, 0.f, 0.f};

    #pragma unroll
    for (int t = 0; t < 4; ++t)
        #pragma unroll
        for (int kk = 0; kk < 4; ++kk)
            acc[t] = __builtin_amdgcn_mfma_f32_16x16x32_bf16(af[kk], bfr[t][kk], acc[t], 0, 0, 0);

    #pragma unroll
    for (int t = 0; t < 4; ++t) {
        const int col = t * 16 + (lane & 15);
        #pragma unroll
        for (int r = 0; r < 4; ++r) {
            const int row = rowbase + (lane >> 4) * 4 + r;
            if (row < n_nodes) {
                const float v = fmaxf(acc[t][r] + bias[t], 0.0f);
                if (OUT_F32) {
                    ((float*)outA)[row * 64 + col] = v;
                } else {
                    if (col < 32) ((unsigned short*)outA)[row * 32 + col] = f2bf(v);
                    else          ((unsigned short*)outB)[row * 32 + col - 32] = f2bf(v);
                }
            }
        }
    }
}

extern "C" void kernel_launch(void* const* d_in, const int* in_sizes, int n_in,
                              void* d_out, int out_size, void* d_ws, size_t ws_size,
                              hipStream_t stream) {
    const float* node_feats = (const float*)d_in[0];
    const int*   edge_src   = (const int*)  d_in[1];
    const int*   edge_dst   = (const int*)  d_in[2];
    const float* edge_w     = (const float*)d_in[3];
    const float* W0         = (const float*)d_in[4];
    const float* b0         = (const float*)d_in[5];
    const float* W1         = (const float*)d_in[6];
    const float* b1         = (const float*)d_in[7];

    const int n_nodes = in_sizes[0] / D;   // 50000
    const int n_edges = in_sizes[1];       // 800000

    // workspace layout (all >=256B aligned)
    char* ws = (char*)d_ws;
    int*            row_off = (int*)ws;                        // 200004 B
    unsigned short* Wpack   = (unsigned short*)(ws + 204800);  // 16 KB
    const size_t base = 237568;
    unsigned short* XA0 = (unsigned short*)(ws + base);               // 3.2 MB
    unsigned short* XB0 = (unsigned short*)(ws + base + 3200000);     // 3.2 MB
    unsigned short* XA1 = (unsigned short*)(ws + base + 6400000);     // 3.2 MB
    unsigned short* XB1 = (unsigned short*)(ws + base + 9600000);     // 3.2 MB
    unsigned short* M   = (unsigned short*)(ws + base + 12800000);    // 6.4 MB

    const int cvtb = (n_nodes * 16 + 255) / 256;          // 3125
    const int offb = (n_edges + 1 + 255) / 256;           // 3130
    prep_kernel<<<cvtb + 32 + offb, 256, 0, stream>>>(node_feats, edge_dst, W0, W1,
                                                      row_off, Wpack, XA0, XB0,
                                                      n_nodes, n_edges, cvtb);

    // persistent agg grid: exactly-resident blocks so blockIdx&1 <-> XCD parity
    // holds for the whole dispatch (capture-safe occupancy query, r14-verified)
    int numCU = 304, maxB = 8, dev = 0;
    hipGetDevice(&dev);
    hipDeviceGetAttribute(&numCU, hipDeviceAttributeMultiprocessorCount, dev);
    hipOccupancyMaxActiveBlocksPerMultiprocessor(&maxB, (const void*)aggregate_kernel, 256, 0);
    if (maxB < 1) maxB = 1;
    int agrid = numCU * maxB;
    if (agrid > 4096) agrid = 4096;
    agrid &= ~1;                                  // even split across chunks
    if (agrid < 2) agrid = 2;
    const int nwaves_c = (agrid / 2) * 4;

    const int ntiles = (n_nodes + 15) / 16;       // 3125
    const int ggrid  = (ntiles + 3) / 4;          // 782

    // layer 0
    aggregate_kernel<<<agrid, 256, 0, stream>>>(XA0, XB0, M, row_off, edge_src, edge_w,
                                                n_nodes, nwaves_c);
    gemm_mfma<0><<<ggrid, 256, 0, stream>>>(XA0, XB0, M, Wpack, b0, b1,
                                            XA1, XB1, ntiles, n_nodes);
    // layer 1
    aggregate_kernel<<<agrid, 256, 0, stream>>>(XA1, XB1, M, row_off, edge_src, edge_w,
                                                n_nodes, nwaves_c);
    gemm_mfma<1><<<ggrid, 256, 0, stream>>>(XA1, XB1, M, Wpack, b0, b1,
                                            d_out, nullptr, ntiles, n_nodes);
}

// Round 17
// 65.233 us; speedup vs baseline: 1.4347x; 1.4347x over previous
//
#include <hip/hip_runtime.h>

#define D 64
#define EPSV 1e-9f

typedef __attribute__((ext_vector_type(8))) short bf8_t;   // 8 x bf16
typedef __attribute__((ext_vector_type(4))) float f4_t;

__device__ inline float bf2f(short u) {
    union { unsigned int i; float f; } v;
    v.i = ((unsigned int)(unsigned short)u) << 16;
    return v.f;
}
__device__ inline unsigned short f2bf(float f) {  // round-nearest-even
    union { float f; unsigned int i; } v; v.f = f;
    unsigned int r = v.i + 0x7fff + ((v.i >> 16) & 1);
    return (unsigned short)(r >> 16);
}

// --- Fused prep: cvt | wpack | row_off boundary scatter (r12-exact) ---
__global__ void prep_kernel(const float* __restrict__ node_feats,
                            const int*   __restrict__ edge_dst,
                            const float* __restrict__ W0,
                            const float* __restrict__ W1,
                            int* __restrict__ row_off,
                            unsigned short* __restrict__ Wpack,
                            unsigned short* __restrict__ X,   // [n][64] bf16
                            int n_nodes, int n_edges, int cvtb)
{
    const int bid = blockIdx.x, tid = threadIdx.x;
    if (bid < cvtb) {
        const int i = bid * 256 + tid;
        if (i < n_nodes * 16) {
            const float4 v = ((const float4*)node_feats)[i];
            const int row = i >> 4, c4 = (i & 15) * 4;
            unsigned short* p = X + row * 64 + c4;
            p[0] = f2bf(v.x); p[1] = f2bf(v.y); p[2] = f2bf(v.z); p[3] = f2bf(v.w);
        }
    } else if (bid < cvtb + 32) {
        // Wpack[((t*4+kk)*64+lane)*8+j] = W[k][col], k=kk*32+(lane>>4)*8+j, col=t*16+(lane&15)
        const int idx = (bid - cvtb) * 256 + tid;
        const int j = idx & 7, lane = (idx >> 3) & 63, kk = (idx >> 9) & 3, t = idx >> 11;
        const int k = kk * 32 + (lane >> 4) * 8 + j;
        const int d = t * 16 + (lane & 15);
        const float v = (k < D) ? W0[d * D + k] : W1[d * D + (k - D)];
        Wpack[idx] = f2bf(v);
    } else {
        const int i = (bid - cvtb - 32) * 256 + tid;   // i in [0, n_edges]
        if (i <= n_edges) {
            const int prev = (i == 0) ? -1 : edge_dst[i - 1];
            const int cur  = (i == n_edges) ? n_nodes : edge_dst[i];
            for (int n = prev + 1; n <= cur; ++n) row_off[n] = i;
        }
    }
}

// --- one batch of 4 rounds: edges [b, b+8) of this lane's node ---
__device__ __forceinline__ void agg_batch8(
    const unsigned short* __restrict__ X,
    const int* __restrict__ edge_src, const float* __restrict__ edge_w,
    int s, int e, int b, int slot, int fo,
    float acc[8], float& wsum)
{
    float w[4]; int sc[4];
    #pragma unroll
    for (int r = 0; r < 4; ++r) {
        const int  ej = s + b + r * 2 + slot;
        const bool v  = ej < e;
        w[r]  = v ? edge_w[ej] : 0.f;
        sc[r] = v ? edge_src[ej] : 0;
    }
    bf8_t f[4];
    #pragma unroll
    for (int r = 0; r < 4; ++r) f[r] = *(const bf8_t*)(X + sc[r] * 64 + fo);
    #pragma unroll
    for (int r = 0; r < 4; ++r) {
        #pragma unroll
        for (int m = 0; m < 8; ++m) acc[m] = fmaf(w[r], bf2f(f[r][m]), acc[m]);
        wsum += w[r];
    }
}

// --- Aggregate: 4 nodes/wave (quarter-wave each), 8 gather instrs in flight.
// Standalone (no barrier/LDS/MFMA coupling). lb(256,6): VGPR cap 85, no spill.
__global__ __launch_bounds__(256, 6) void aggregate_kernel(
    const unsigned short* __restrict__ X,   // [n][64] bf16
    unsigned short* __restrict__ M,         // [n][64] bf16 msg out
    const int*   __restrict__ row_off,
    const int*   __restrict__ edge_src,
    const float* __restrict__ edge_w,
    int n_nodes)
{
    const int lane = threadIdx.x & 63;
    const int wib  = threadIdx.x >> 6;

    const int q    = lane >> 4;          // quarter = node select (0..3)
    const int slot = (lane >> 3) & 1;    // 2 edge slots per node
    const int fo   = (lane & 7) * 8;     // 16B piece of the 128B row

    int node = (blockIdx.x * 4 + wib) * 4 + q;
    if (node >= n_nodes) node = n_nodes - 1;   // dup writes identical data

    const int s = row_off[node];
    const int e = row_off[node + 1];
    int dm = e - s;
    dm = max(dm, __shfl_xor(dm, 16));
    dm = max(dm, __shfl_xor(dm, 32));    // wave-uniform max over the 4 nodes

    float acc[8];
    #pragma unroll
    for (int m = 0; m < 8; ++m) acc[m] = 0.f;
    float wsum = 0.f;

    // edges 0-15: two batch8 calls = 8 gather instrs, issued back-to-back
    agg_batch8(X, edge_src, edge_w, s, e, 0, slot, fo, acc, wsum);
    agg_batch8(X, edge_src, edge_w, s, e, 8, slot, fo, acc, wsum);
    if (dm > 16) {
        agg_batch8(X, edge_src, edge_w, s, e, 16, slot, fo, acc, wsum);
        agg_batch8(X, edge_src, edge_w, s, e, 24, slot, fo, acc, wsum);
    }
    for (int base = 32; base < dm; base += 16) {   // rare tail
        agg_batch8(X, edge_src, edge_w, s, e, base, slot, fo, acc, wsum);
        agg_batch8(X, edge_src, edge_w, s, e, base + 8, slot, fo, acc, wsum);
    }

    // combine the 2 slots (lane bit 3)
    #pragma unroll
    for (int m = 0; m < 8; ++m) acc[m] += __shfl_xor(acc[m], 8);
    wsum += __shfl_xor(wsum, 8);

    if ((lane & 8) == 0) {               // slot-0 lanes: 8 x 16B = full msg row
        const float inv = 1.0f / (wsum + EPSV);
        bf8_t mv;
        #pragma unroll
        for (int m = 0; m < 8; ++m) mv[m] = (short)f2bf(acc[m] * inv);
        *(bf8_t*)(M + node * 64 + fo) = mv;
    }
}

// --- MFMA GEMM (r12-exact): wave = one 16-row tile ---
template<int OUT_F32>
__global__ __launch_bounds__(256, 4) void gemm_mfma(
    const unsigned short* __restrict__ X,      // [n][64] bf16
    const unsigned short* __restrict__ M,      // [n][64] bf16
    const unsigned short* __restrict__ Wpack,  // fragment-packed, 8192 bf16
    const float* __restrict__ b0,
    const float* __restrict__ b1,
    void* __restrict__ outp,
    int ntiles, int n_nodes)
{
    const int lane = threadIdx.x & 63;
    const int wib  = threadIdx.x >> 6;
    const int tile = __builtin_amdgcn_readfirstlane(blockIdx.x * 4 + wib);
    if (tile >= ntiles) return;

    bf8_t bfr[4][4];
    #pragma unroll
    for (int t = 0; t < 4; ++t)
        #pragma unroll
        for (int kk = 0; kk < 4; ++kk)
            bfr[t][kk] = *(const bf8_t*)(Wpack + ((t * 4 + kk) * 64 + lane) * 8);

    float bias[4];
    #pragma unroll
    for (int t = 0; t < 4; ++t) {
        const int col = t * 16 + (lane & 15);
        bias[t] = b0[col] + b1[col];
    }

    const int koff = (lane >> 4) * 8;
    const int rowbase = tile * 16;
    int arow = rowbase + (lane & 15); if (arow >= n_nodes) arow = n_nodes - 1;

    bf8_t af[4];
    af[0] = *(const bf8_t*)(X + arow * 64 + koff);        // k  0..31
    af[1] = *(const bf8_t*)(X + arow * 64 + 32 + koff);   // k 32..63
    af[2] = *(const bf8_t*)(M + arow * 64 + koff);        // k 64..95
    af[3] = *(const bf8_t*)(M + arow * 64 + 32 + koff);   // k 96..127

    f4_t acc[4];
    #pragma unroll
    for (int t = 0; t < 4; ++t) acc[t] = (f4_t){0.f, 0.f, 0.f, 0.f};

    #pragma unroll
    for (int t = 0; t < 4; ++t)
        #pragma unroll
        for (int kk = 0; kk < 4; ++kk)
            acc[t] = __builtin_amdgcn_mfma_f32_16x16x32_bf16(af[kk], bfr[t][kk], acc[t], 0, 0, 0);

    #pragma unroll
    for (int t = 0; t < 4; ++t) {
        const int col = t * 16 + (lane & 15);
        #pragma unroll
        for (int r = 0; r < 4; ++r) {
            const int row = rowbase + (lane >> 4) * 4 + r;
            if (row < n_nodes) {
                const float v = fmaxf(acc[t][r] + bias[t], 0.0f);
                if (OUT_F32) ((float*)outp)[row * 64 + col] = v;
                else         ((unsigned short*)outp)[row * 64 + col] = f2bf(v);
            }
        }
    }
}

extern "C" void kernel_launch(void* const* d_in, const int* in_sizes, int n_in,
                              void* d_out, int out_size, void* d_ws, size_t ws_size,
                              hipStream_t stream) {
    const float* node_feats = (const float*)d_in[0];
    const int*   edge_src   = (const int*)  d_in[1];
    const int*   edge_dst   = (const int*)  d_in[2];
    const float* edge_w     = (const float*)d_in[3];
    const float* W0         = (const float*)d_in[4];
    const float* b0         = (const float*)d_in[5];
    const float* W1         = (const float*)d_in[6];
    const float* b1         = (const float*)d_in[7];

    const int n_nodes = in_sizes[0] / D;   // 50000
    const int n_edges = in_sizes[1];       // 800000

    // workspace layout (all >=256B aligned)
    char* ws = (char*)d_ws;
    int*            row_off = (int*)ws;                        // 200004 B
    unsigned short* Wpack   = (unsigned short*)(ws + 204800);  // 16 KB
    const size_t base = 237568;
    unsigned short* X0 = (unsigned short*)(ws + base);               // 6.4 MB
    unsigned short* X1 = (unsigned short*)(ws + base + 6400000);     // 6.4 MB
    unsigned short* M  = (unsigned short*)(ws + base + 12800000);    // 6.4 MB

    const int cvtb = (n_nodes * 16 + 255) / 256;          // 3125
    const int offb = (n_edges + 1 + 255) / 256;           // 3130
    prep_kernel<<<cvtb + 32 + offb, 256, 0, stream>>>(node_feats, edge_dst, W0, W1,
                                                      row_off, Wpack, X0,
                                                      n_nodes, n_edges, cvtb);

    const int agrid  = (n_nodes + 15) / 16;      // 4 nodes/wave, 4 waves/block: 3125
    const int ntiles = (n_nodes + 15) / 16;      // 3125
    const int ggrid  = (ntiles + 3) / 4;         // 782

    // layer 0
    aggregate_kernel<<<agrid, 256, 0, stream>>>(X0, M, row_off, edge_src, edge_w, n_nodes);
    gemm_mfma<0><<<ggrid, 256, 0, stream>>>(X0, M, Wpack, b0, b1, X1, ntiles, n_nodes);
    // layer 1
    aggregate_kernel<<<agrid, 256, 0, stream>>>(X1, M, row_off, edge_src, edge_w, n_nodes);
    gemm_mfma<1><<<ggrid, 256, 0, stream>>>(X1, M, Wpack, b0, b1, d_out, ntiles, n_nodes);
}

// Round 18
// 61.839 us; speedup vs baseline: 1.5134x; 1.0549x over previous
//
#include <hip/hip_runtime.h>

#define D 64
#define EPSV 1e-9f

typedef __attribute__((ext_vector_type(8))) short bf8_t;   // 8 x bf16
typedef __attribute__((ext_vector_type(4))) float f4_t;

__device__ inline float bf2f(short u) {
    union { unsigned int i; float f; } v;
    v.i = ((unsigned int)(unsigned short)u) << 16;
    return v.f;
}
__device__ inline unsigned short f2bf(float f) {  // round-nearest-even
    union { float f; unsigned int i; } v; v.f = f;
    unsigned int r = v.i + 0x7fff + ((v.i >> 16) & 1);
    return (unsigned short)(r >> 16);
}

// --- Fused prep: cvt (blocks [0,cvtb)) | wpack (next 32) | row_off scatter (rest) ---
__global__ void prep_kernel(const float* __restrict__ node_feats,
                            const int*   __restrict__ edge_dst,
                            const float* __restrict__ W0,
                            const float* __restrict__ W1,
                            int* __restrict__ row_off,
                            unsigned short* __restrict__ Wpack,
                            unsigned short* __restrict__ X,   // [n][64] bf16
                            int n_nodes, int n_edges, int cvtb)
{
    const int bid = blockIdx.x;
    const int tid = threadIdx.x;
    if (bid < cvtb) {
        const int i = bid * 256 + tid;           // one per 4 floats
        if (i < n_nodes * 16) {
            const float4 v = ((const float4*)node_feats)[i];
            const int row = i >> 4, c4 = (i & 15) * 4;
            unsigned short* p = X + row * 64 + c4;
            p[0] = f2bf(v.x); p[1] = f2bf(v.y); p[2] = f2bf(v.z); p[3] = f2bf(v.w);
        }
    } else if (bid < cvtb + 32) {
        // Wpack[((t*4+kk)*64+lane)*8+j] = W[k][col], k=kk*32+(lane>>4)*8+j, col=t*16+(lane&15)
        const int idx = (bid - cvtb) * 256 + tid;
        const int j = idx & 7, lane = (idx >> 3) & 63, kk = (idx >> 9) & 3, t = idx >> 11;
        const int k = kk * 32 + (lane >> 4) * 8 + j;
        const int d = t * 16 + (lane & 15);
        const float v = (k < D) ? W0[d * D + k] : W1[d * D + (k - D)];
        Wpack[idx] = f2bf(v);
    } else {
        // row_off[n] = first edge with dst >= n (boundary scatter on sorted dst)
        const int i = (bid - cvtb - 32) * 256 + tid;   // i in [0, n_edges]
        if (i <= n_edges) {
            const int prev = (i == 0) ? -1 : edge_dst[i - 1];
            const int cur  = (i == n_edges) ? n_nodes : edge_dst[i];
            for (int n = prev + 1; n <= cur; ++n) row_off[n] = i;
        }
    }
}

// --- Aggregate: 2 nodes/wave; half-wave = 4 slots x 8 lanes x 16B.
// One gather instr = 4 edges x full 64-dim row (per node).
// Rounds 0-3 batched (4 gathers + 8 meta in flight); 4-7 behind uniform deg>16.
__global__ __launch_bounds__(256, 8) void aggregate_kernel(
    const unsigned short* __restrict__ X,   // [n][64] bf16
    unsigned short* __restrict__ M,         // [n][64] bf16 msg out
    const int*   __restrict__ row_off,
    const int*   __restrict__ edge_src,
    const float* __restrict__ edge_w,
    int n_nodes)
{
    const int lane = threadIdx.x & 63;
    const int wib  = threadIdx.x >> 6;
    const int h    = lane >> 5;                    // half-wave = node select
    int node = blockIdx.x * 8 + wib * 2 + h;
    if (node >= n_nodes) node = n_nodes - 1;

    const int s = row_off[node];
    const int e = row_off[node + 1];
    const int deg = e - s;
    const int od  = __shfl_xor(deg, 32);
    const int degmax = deg > od ? deg : od;        // wave-uniform

    const int slot = (lane >> 3) & 3;   // 0..3 within half-wave
    const int fo   = (lane & 7) * 8;    // 8-dim (16B) piece of 64-dim row

    float acc[8];
    #pragma unroll
    for (int m = 0; m < 8; ++m) acc[m] = 0.f;
    float wsum = 0.f;

    // rounds 0-3: meta batched, then 4 independent full-row gathers
    {
        float w[4]; int sc[4];
        #pragma unroll
        for (int r = 0; r < 4; ++r) {
            const int  ej = s + r * 4 + slot;
            const bool v  = ej < e;
            w[r]  = v ? edge_w[ej] : 0.f;
            sc[r] = v ? edge_src[ej] : 0;
        }
        bf8_t f[4];
        #pragma unroll
        for (int r = 0; r < 4; ++r) f[r] = *(const bf8_t*)(X + sc[r] * 64 + fo);
        #pragma unroll
        for (int r = 0; r < 4; ++r) {
            #pragma unroll
            for (int m = 0; m < 8; ++m) acc[m] = fmaf(w[r], bf2f(f[r][m]), acc[m]);
            wsum += w[r];
        }
    }
    if (degmax > 16) {   // rounds 4-7 (wave-uniform branch)
        float w[4]; int sc[4];
        #pragma unroll
        for (int r = 0; r < 4; ++r) {
            const int  ej = s + 16 + r * 4 + slot;
            const bool v  = ej < e;
            w[r]  = v ? edge_w[ej] : 0.f;
            sc[r] = v ? edge_src[ej] : 0;
        }
        bf8_t f[4];
        #pragma unroll
        for (int r = 0; r < 4; ++r) f[r] = *(const bf8_t*)(X + sc[r] * 64 + fo);
        #pragma unroll
        for (int r = 0; r < 4; ++r) {
            #pragma unroll
            for (int m = 0; m < 8; ++m) acc[m] = fmaf(w[r], bf2f(f[r][m]), acc[m]);
            wsum += w[r];
        }
    }
    // rare tail: deg > 32, 16 edges per trip (uniform trip count)
    for (int base = 32; base < degmax; base += 16) {
        float w[4]; int sc[4];
        #pragma unroll
        for (int r = 0; r < 4; ++r) {
            const int  ej = s + base + r * 4 + slot;
            const bool v  = ej < e;
            w[r]  = v ? edge_w[ej] : 0.f;
            sc[r] = v ? edge_src[ej] : 0;
        }
        bf8_t f[4];
        #pragma unroll
        for (int r = 0; r < 4; ++r) f[r] = *(const bf8_t*)(X + sc[r] * 64 + fo);
        #pragma unroll
        for (int r = 0; r < 4; ++r) {
            #pragma unroll
            for (int m = 0; m < 8; ++m) acc[m] = fmaf(w[r], bf2f(f[r][m]), acc[m]);
            wsum += w[r];
        }
    }

    // butterfly over slot bits (lane bits 3,4) -- stays within half-wave
    #pragma unroll
    for (int off = 8; off <= 16; off <<= 1) {
        #pragma unroll
        for (int m = 0; m < 8; ++m) acc[m] += __shfl_xor(acc[m], off);
        wsum += __shfl_xor(wsum, off);
    }

    const float inv = 1.0f / (wsum + EPSV);
    if (slot == 0) {                   // 8 lanes per node x 16B = full 128B msg row
        bf8_t mv;
        #pragma unroll
        for (int m = 0; m < 8; ++m) mv[m] = (short)f2bf(acc[m] * inv);
        *(bf8_t*)(M + node * 64 + fo) = mv;
    }
}

// --- MFMA GEMM: out = relu([X|M] @ [W0';W1'] + b0 + b1). Wave = one 16-row tile.
template<int OUT_F32>
__global__ __launch_bounds__(256, 4) void gemm_mfma(
    const unsigned short* __restrict__ X,      // [n][64] bf16
    const unsigned short* __restrict__ M,      // [n][64] bf16
    const unsigned short* __restrict__ Wpack,  // fragment-packed, 8192 bf16
    const float* __restrict__ b0,
    const float* __restrict__ b1,
    void* __restrict__ outp,
    int ntiles, int n_nodes)
{
    const int lane = threadIdx.x & 63;
    const int wib  = threadIdx.x >> 6;
    const int tile = __builtin_amdgcn_readfirstlane(blockIdx.x * 4 + wib);
    if (tile >= ntiles) return;

    bf8_t bfr[4][4];
    #pragma unroll
    for (int t = 0; t < 4; ++t)
        #pragma unroll
        for (int kk = 0; kk < 4; ++kk)
            bfr[t][kk] = *(const bf8_t*)(Wpack + ((t * 4 + kk) * 64 + lane) * 8);

    float bias[4];
    #pragma unroll
    for (int t = 0; t < 4; ++t) {
        const int col = t * 16 + (lane & 15);
        bias[t] = b0[col] + b1[col];
    }

    const int koff = (lane >> 4) * 8;
    const int rowbase = tile * 16;
    int arow = rowbase + (lane & 15); if (arow >= n_nodes) arow = n_nodes - 1;

    bf8_t af[4];
    af[0] = *(const bf8_t*)(X + arow * 64 + koff);        // k  0..31
    af[1] = *(const bf8_t*)(X + arow * 64 + 32 + koff);   // k 32..63
    af[2] = *(const bf8_t*)(M + arow * 64 + koff);        // k 64..95
    af[3] = *(const bf8_t*)(M + arow * 64 + 32 + koff);   // k 96..127

    f4_t acc[4];
    #pragma unroll
    for (int t = 0; t < 4; ++t) acc[t] = (f4_t){0.f, 0.f, 0.f, 0.f};

    #pragma unroll
    for (int t = 0; t < 4; ++t)
        #pragma unroll
        for (int kk = 0; kk < 4; ++kk)
            acc[t] = __builtin_amdgcn_mfma_f32_16x16x32_bf16(af[kk], bfr[t][kk], acc[t], 0, 0, 0);

    #pragma unroll
    for (int t = 0; t < 4; ++t) {
        const int col = t * 16 + (lane & 15);
        #pragma unroll
        for (int r = 0; r < 4; ++r) {
            const int row = rowbase + (lane >> 4) * 4 + r;
            if (row < n_nodes) {
                const float v = fmaxf(acc[t][r] + bias[t], 0.0f);
                if (OUT_F32) ((float*)outp)[row * 64 + col] = v;
                else         ((unsigned short*)outp)[row * 64 + col] = f2bf(v);
            }
        }
    }
}

extern "C" void kernel_launch(void* const* d_in, const int* in_sizes, int n_in,
                              void* d_out, int out_size, void* d_ws, size_t ws_size,
                              hipStream_t stream) {
    const float* node_feats = (const float*)d_in[0];
    const int*   edge_src   = (const int*)  d_in[1];
    const int*   edge_dst   = (const int*)  d_in[2];
    const float* edge_w     = (const float*)d_in[3];
    const float* W0         = (const float*)d_in[4];
    const float* b0         = (const float*)d_in[5];
    const float* W1         = (const float*)d_in[6];
    const float* b1         = (const float*)d_in[7];

    const int n_nodes = in_sizes[0] / D;   // 50000
    const int n_edges = in_sizes[1];       // 800000

    // workspace layout (all >=256B aligned)
    char* ws = (char*)d_ws;
    int*            row_off = (int*)ws;                        // 200004 B
    unsigned short* Wpack   = (unsigned short*)(ws + 204800);  // 16 KB
    const size_t base = 237568;
    unsigned short* X0 = (unsigned short*)(ws + base);               // 6.4 MB
    unsigned short* X1 = (unsigned short*)(ws + base + 6400000);     // 6.4 MB
    unsigned short* M  = (unsigned short*)(ws + base + 12800000);    // 6.4 MB

    const int cvtb = (n_nodes * 16 + 255) / 256;          // 3125
    const int offb = (n_edges + 1 + 255) / 256;           // 3130
    prep_kernel<<<cvtb + 32 + offb, 256, 0, stream>>>(node_feats, edge_dst, W0, W1,
                                                      row_off, Wpack, X0,
                                                      n_nodes, n_edges, cvtb);

    const int agrid  = (n_nodes + 7) / 8;        // 2 nodes/wave, 4 waves/block: 6250
    const int ntiles = (n_nodes + 15) / 16;      // 3125
    const int ggrid  = (ntiles + 3) / 4;         // 1 tile/wave: 782 blocks (~3/CU)

    // layer 0
    aggregate_kernel<<<agrid, 256, 0, stream>>>(X0, M, row_off, edge_src, edge_w, n_nodes);
    gemm_mfma<0><<<ggrid, 256, 0, stream>>>(X0, M, Wpack, b0, b1, X1, ntiles, n_nodes);
    // layer 1
    aggregate_kernel<<<agrid, 256, 0, stream>>>(X1, M, row_off, edge_src, edge_w, n_nodes);
    gemm_mfma<1><<<ggrid, 256, 0, stream>>>(X1, M, Wpack, b0, b1, d_out, ntiles, n_nodes);
}